// Round 3
// baseline (5066.773 us; speedup 1.0000x reference)
//
#include <hip/hip_runtime.h>
#include <hip/hip_bf16.h>

typedef __bf16 bf16x8 __attribute__((ext_vector_type(8)));
typedef float  f32x4  __attribute__((ext_vector_type(4)));

#define MFMA_BF16(a, b, c) __builtin_amdgcn_mfma_f32_16x16x32_bf16((a), (b), (c), 0, 0, 0)

constexpr int TT = 160, BB = 2048, HH = 512, EE = 64, VV = 128, G3 = 1536;
constexpr size_t LPROB_ELEMS = (size_t)TT * BB * VV;  // 41,943,040

__device__ __forceinline__ float fsigmoid(float x) {
  return 1.0f / (1.0f + __expf(-x));
}
__device__ __forceinline__ float ftanh(float x) {
  float ax = fabsf(x);
  float e = __expf(-2.0f * ax);
  float r = (1.0f - e) / (1.0f + e);
  return x < 0.0f ? -r : r;
}
// dual-dtype scalar load: isbf ? bf16[i] : f32[i]
__device__ __forceinline__ float ld(const void* p, long i, int isbf) {
  return isbf ? (float)((const __bf16*)p)[i] : ((const float*)p)[i];
}

// ---------------- dtype probe ----------------
// Inspect encoder_hidden's first 4096 16-bit words as bf16. True-bf16 N(0,1)
// data: ~100% have exponent field in [90,150] (or are zero). fp32 data read
// as bf16: low-mantissa halves have uniform exponent -> ~62% plausible.
// Threshold at 75%.
__global__ __launch_bounds__(256) void probe_dtype(
    const unsigned short* __restrict__ eh, int* __restrict__ flagp) {
  __shared__ int sb[256];
  int tid = threadIdx.x;
  int cnt = 0;
  for (int i = tid; i < 4096; i += 256) {
    unsigned short u = eh[i];
    int e = (u >> 7) & 0xFF;
    if ((u & 0x7FFF) == 0 || (e >= 90 && e <= 150)) cnt++;
  }
  sb[tid] = cnt;
  __syncthreads();
  for (int s = 128; s > 0; s >>= 1) {
    if (tid < s) sb[tid] += sb[tid + s];
    __syncthreads();
  }
  if (tid == 0) *flagp = (sb[0] > 3072) ? 1 : 0;
}

// ---------------- prep kernels ----------------

// Normalize weights into internal buffers: Whh_b/Wout_b (bf16), bhhn_f/bout_f (f32)
__global__ __launch_bounds__(256) void conv_w(
    const void* __restrict__ Whh, const void* __restrict__ Wout,
    const void* __restrict__ bhh, const void* __restrict__ bout,
    const int* __restrict__ flagp,
    __bf16* __restrict__ Whh_b, __bf16* __restrict__ Wout_b,
    float* __restrict__ bhhn_f, float* __restrict__ bout_f) {
  const int isbf = *flagp;
  int idx = blockIdx.x * 256 + threadIdx.x;   // 3072 blocks -> 786,432 = 1536*512
  Whh_b[idx] = (__bf16)ld(Whh, idx, isbf);
  if (idx < VV * HH) Wout_b[idx] = (__bf16)ld(Wout, idx, isbf);
  if (idx < HH) bhhn_f[idx] = ld(bhh, 2 * HH + idx, isbf);
  if (idx < VV) bout_f[idx] = ld(bout, idx, isbf);
}

// gi_vocab[v][n] = relu(emb[v]) . W_ih[n] + b_ih[n] + (n < 1024 ? b_hh[n] : 0)
// (b_hh n-slice NOT folded: it sits inside r * (gh_n + b_hh_n))
__global__ __launch_bounds__(256) void prep_gi(
    const void* __restrict__ emb, const void* __restrict__ Wih,
    const void* __restrict__ bih, const void* __restrict__ bhh,
    const int* __restrict__ flagp, float* __restrict__ gi) {
  const int isbf = *flagp;
  int idx = blockIdx.x * 256 + threadIdx.x;   // 768 blocks -> exactly 128*1536
  int v = idx / G3;
  int n = idx - v * G3;
  float s = 0.0f;
#pragma unroll 8
  for (int k = 0; k < EE; ++k) {
    float x = ld(emb, v * EE + k, isbf);
    x = x > 0.0f ? x : 0.0f;
    s += x * ld(Wih, (long)n * EE + k, isbf);
  }
  s += ld(bih, n, isbf);
  if (n < 2 * HH) s += ld(bhh, n, isbf);
  gi[idx] = s;
}

// h0 = encoder_hidden[0]: fp32 state + bf16 mirror for MFMA
__global__ __launch_bounds__(256) void prep_h0(
    const void* __restrict__ ehid, const int* __restrict__ flagp,
    float* __restrict__ hf, __bf16* __restrict__ hb0) {
  const int isbf = *flagp;
  int idx = blockIdx.x * 256 + threadIdx.x;   // 4096 blocks -> 1,048,576 = 2048*512
  float v = ld(ehid, idx, isbf);
  hf[idx] = v;
  hb0[idx] = (__bf16)v;
}

// ---------------- per-step kernel ----------------
// Grid 640 x 256, launched 161 times (t = 0..160). Kernel boundaries provide
// the per-step device-wide sync + coherence.
// Blocks [0,512): phase 1 (t<160): h(t) = GRU(h(t-1), tok(t)); t==160: copy
//   final hidden to output. Blocks [512,640): phase 2 (t>=1): logits +
//   log_softmax of h(t-1), 16 rows each.
// MFMA 16x16x32 bf16 layouts (HW-verified):
//   A: lane holds A[m=lane&15][k=quad*8+j]   B: same for B rows
//   D: col=lane&15, row=quad*4+reg
__global__ __launch_bounds__(256) void gru_step(
    const __bf16* __restrict__ Whh, const __bf16* __restrict__ Wout,
    const float* __restrict__ bhhn_f, const float* __restrict__ bout_f,
    const float* __restrict__ gi, const int* __restrict__ tgt,
    const int* __restrict__ flagp,
    const __bf16* __restrict__ hbs,   // h(t-1) bf16
    __bf16* __restrict__ hbd,         // h(t) bf16 (written)
    float* __restrict__ hf,           // h f32, single buffer (own-element RMW)
    void* __restrict__ outp, int t) {
  __shared__ float llds[16 * 132];

  const int tid = threadIdx.x;
  const int bid = blockIdx.x;
  const int w = tid >> 6;
  const int lane = tid & 63;
  const int q = lane >> 4;
  const int l16 = lane & 15;
  const int isbf = *flagp;
  const f32x4 fzero = {0.0f, 0.0f, 0.0f, 0.0f};

  if (bid < 512) {
    if (t == 160) {
      // final hidden: outp[LPROB + idx] = hf[idx] in output dtype
      int base = bid * 2048 + tid * 8;
      const float* src = hf + base;
      if (isbf) {
        bf16x8 v;
#pragma unroll
        for (int i = 0; i < 8; ++i) v[i] = (__bf16)src[i];
        *(bf16x8*)((__bf16*)outp + LPROB_ELEMS + base) = v;
      } else {
        f32x4 v0 = *(const f32x4*)src;
        f32x4 v1 = *(const f32x4*)(src + 4);
        float* dst = (float*)outp + LPROB_ELEMS + base;
        *(f32x4*)dst = v0;
        *(f32x4*)(dst + 4) = v1;
      }
      return;
    }
    const int grp = bid & 15;
    const int colTile = bid >> 4;
    const int mBase = grp * 128 + w * 32;

    // ---- gh = h(t-1) @ W_hh^T for [128 rows x (3 gates x 16 cols)] tile ----
    f32x4 acc[2][3];
#pragma unroll
    for (int ms = 0; ms < 2; ++ms)
#pragma unroll
      for (int gg = 0; gg < 3; ++gg) acc[ms][gg] = fzero;

    const __bf16* aRow0 = hbs + (size_t)(mBase + l16) * HH + q * 8;
    const __bf16* aRow1 = aRow0 + 16 * HH;
    const __bf16* bRow = Whh + (size_t)(colTile * 16 + l16) * HH + q * 8;

#pragma unroll 4
    for (int k0 = 0; k0 < HH; k0 += 32) {
      bf16x8 a0 = *(const bf16x8*)(aRow0 + k0);
      bf16x8 a1 = *(const bf16x8*)(aRow1 + k0);
#pragma unroll
      for (int gg = 0; gg < 3; ++gg) {
        bf16x8 bf = *(const bf16x8*)(bRow + (size_t)gg * (HH * HH) + k0);
        acc[0][gg] = MFMA_BF16(a0, bf, acc[0][gg]);
        acc[1][gg] = MFMA_BF16(a1, bf, acc[1][gg]);
      }
    }

    const int c = colTile * 16 + l16;
    const float bhhn = bhhn_f[c];

#pragma unroll
    for (int ms = 0; ms < 2; ++ms) {
#pragma unroll
      for (int rg = 0; rg < 4; ++rg) {
        int row = mBase + ms * 16 + q * 4 + rg;
        int tk = (t == 0) ? 0 : tgt[row * TT + (t - 1)];
        const float* gv = gi + (size_t)tk * G3 + c;
        float r_ = fsigmoid(acc[ms][0][rg] + gv[0]);
        float z_ = fsigmoid(acc[ms][1][rg] + gv[HH]);
        float n_ = ftanh(gv[2 * HH] + r_ * (acc[ms][2][rg] + bhhn));
        size_t hi = (size_t)row * HH + c;
        float hv = (1.0f - z_) * n_ + z_ * hf[hi];
        hf[hi] = hv;
        hbd[hi] = (__bf16)hv;
      }
    }
  } else {
    // ---- phase 2: logits + log_softmax of h(t-1) ----
    if (t == 0) return;
    const int rb = (bid - 512) * 16;
    f32x4 acc2[2];
    acc2[0] = fzero; acc2[1] = fzero;
    const __bf16* aR  = hbs + (size_t)(rb + l16) * HH + q * 8;
    const __bf16* bR0 = Wout + (size_t)(w * 32 + l16) * HH + q * 8;
    const __bf16* bR1 = bR0 + 16 * HH;
#pragma unroll 4
    for (int k0 = 0; k0 < HH; k0 += 32) {
      bf16x8 a  = *(const bf16x8*)(aR + k0);
      bf16x8 b0 = *(const bf16x8*)(bR0 + k0);
      bf16x8 b1 = *(const bf16x8*)(bR1 + k0);
      acc2[0] = MFMA_BF16(a, b0, acc2[0]);
      acc2[1] = MFMA_BF16(a, b1, acc2[1]);
    }
#pragma unroll
    for (int j = 0; j < 2; ++j) {
      int col = (w * 2 + j) * 16 + l16;
      float bo = bout_f[col];
#pragma unroll
      for (int rg = 0; rg < 4; ++rg)
        llds[(q * 4 + rg) * 132 + col] = acc2[j][rg] + bo;
    }
    __syncthreads();
    {
      int row = tid >> 4, seg = tid & 15;
      const float* lr = &llds[row * 132 + seg * 8];
      float x[8];
      float m = -3.0e38f;
#pragma unroll
      for (int i = 0; i < 8; ++i) { x[i] = lr[i]; m = fmaxf(m, x[i]); }
#pragma unroll
      for (int d = 1; d < 16; d <<= 1) m = fmaxf(m, __shfl_xor(m, d, 16));
      float s = 0.0f;
#pragma unroll
      for (int i = 0; i < 8; ++i) s += __expf(x[i] - m);
#pragma unroll
      for (int d = 1; d < 16; d <<= 1) s += __shfl_xor(s, d, 16);
      float lg = m + __logf(s);
      size_t ofs = (size_t)(t - 1) * (BB * VV) + (size_t)(rb + row) * VV + seg * 8;
      if (isbf) {
        bf16x8 ov;
#pragma unroll
        for (int i = 0; i < 8; ++i) ov[i] = (__bf16)(x[i] - lg);
        *(bf16x8*)((__bf16*)outp + ofs) = ov;
      } else {
        f32x4 o0, o1;
#pragma unroll
        for (int i = 0; i < 4; ++i) { o0[i] = x[i] - lg; o1[i] = x[4 + i] - lg; }
        float* dst = (float*)outp + ofs;
        *(f32x4*)dst = o0;
        *(f32x4*)(dst + 4) = o1;
      }
    }
  }
}

// ---------------- launcher ----------------
extern "C" void kernel_launch(void* const* d_in, const int* in_sizes, int n_in,
                              void* d_out, int out_size, void* d_ws, size_t ws_size,
                              hipStream_t stream) {
  // setup_inputs order:
  // 0 encoder_outputs (unused), 1 encoder_hidden, 2 target_tensor, 3 embedding,
  // 4 W_ih, 5 W_hh, 6 b_ih, 7 b_hh, 8 W_out, 9 b_out
  const void* ehid = d_in[1];
  const int*  tgt  = (const int*)d_in[2];
  const void* emb  = d_in[3];
  const void* Wih  = d_in[4];
  const void* Whh  = d_in[5];
  const void* bih  = d_in[6];
  const void* bhh  = d_in[7];
  const void* Wout = d_in[8];
  const void* bout = d_in[9];

  // workspace carve: ~10.4 MiB, all offsets 256B-aligned
  char* ws = (char*)d_ws;
  int*    flagp  = (int*)(ws + 0);              //       256 B
  float*  gi     = (float*)(ws + 256);          //   786,432 B: [128][1536] f32
  float*  hf     = (float*)(ws + 786688);       // 4,194,304 B: h f32
  __bf16* hb0    = (__bf16*)(ws + 4980992);     // 2,097,152 B: h bf16 ping
  __bf16* hb1    = (__bf16*)(ws + 7078144);     // 2,097,152 B: h bf16 pong
  __bf16* Whh_b  = (__bf16*)(ws + 9175296);     // 1,572,864 B
  __bf16* Wout_b = (__bf16*)(ws + 10748160);    //   131,072 B
  float*  bhhn_f = (float*)(ws + 10879232);     //     2,048 B
  float*  bout_f = (float*)(ws + 10881280);     //       512 B

  probe_dtype<<<1, 256, 0, stream>>>((const unsigned short*)ehid, flagp);
  conv_w<<<3072, 256, 0, stream>>>(Whh, Wout, bhh, bout, flagp,
                                   Whh_b, Wout_b, bhhn_f, bout_f);
  prep_gi<<<768, 256, 0, stream>>>(emb, Wih, bih, bhh, flagp, gi);
  prep_h0<<<4096, 256, 0, stream>>>(ehid, flagp, hf, hb0);

  for (int t = 0; t <= TT; ++t) {
    const __bf16* hbs = (t & 1) ? hb1 : hb0;   // h(t-1)
    __bf16*       hbd = (t & 1) ? hb0 : hb1;   // h(t)
    gru_step<<<640, 256, 0, stream>>>(Whh_b, Wout_b, bhhn_f, bout_f, gi, tgt,
                                      flagp, hbs, hbd, hf, d_out, t);
  }
}